// Round 6
// baseline (251.842 us; speedup 1.0000x reference)
//
#include <hip/hip_runtime.h>

// GeometryOptimalTransport: B=4, N=M=4096, C=128
// Sinkhorn (3 iters) over log_K(m,n) = -dist2/eps masked to -1e9, then
// attn-weighted gather of source feats.
//
// R2: validity is iteration-invariant -> precompute adjacency once; run all
// 6 lse updates + output on the ~3% dense structure. Finite NEG_INF=-1e9
// contamination is closed-form:
//   - row with 0 valid entries => u = +1e9 EXACTLY (ulp(1e9)=64)
//   - such rows contribute exp(0) to EVERY column lse => per-batch count cc
//   - all other invalid entries underflow to exactly 0 in fp32.
// R5-R8 journal: compaction costs ~60us in ANY form -> permuted bitmap (R7,
// sweep 61us). LDS-staging partners (R8): no change -> the ~70% SIMD-idle in
// the sweep is NOT VMEM latency, NOT LDS, NOT bandwidth; cause unidentified.
// R9: col_bm is the bit TRANSPOSE of row_bm: with the permuted layout, rows
// {m:(m>>1)&63==L'} x cols {n:(n>>1)&63==L} form an exact 64x64 bit tile
// (lane lam <-> m_lam=(lam>>1)*128+2L'+(lam&1), bit k <-> n_k=(k>>1)*128+
// 2L+(k&1)). A 6-step shfl_xor butterfly transposes the tile in registers;
// output lane kap IS W_c(n_kap, L'). Sweep runs row-side only (half the
// blocks) + a ~5us bt_kernel. Doubles as ablation: if sweep time doesn't
// halve with half the blocks, a dispatch-level fixed cost exists.
// R10: R9 bench hit an infra failure ("container failed twice", no pytest/
// counter evidence); kernel re-audited (butterfly orientation verified on
// 4x4 analog, all addresses in-bounds) and resubmitted unchanged.

constexpr int   BB = 4;
constexpr int   NN = 4096;
constexpr int   MM = 4096;
constexpr int   CC = 128;
constexpr float kNegInf    = -1000000000.0f;
constexpr float kThresh2   = 0.04f;                 // 0.2^2
constexpr float kNegInvEps = -(1.0f / 0.01000001f); // -(1/(EPSILON+1e-8))

__device__ inline float wave_reduce_max(float x) {
#pragma unroll
  for (int off = 32; off > 0; off >>= 1)
    x = fmaxf(x, __shfl_xor(x, off, 64));
  return x;
}
__device__ inline float wave_reduce_sum(float x) {
#pragma unroll
  for (int off = 32; off > 0; off >>= 1)
    x += __shfl_xor(x, off, 64);
  return x;
}

// ---------------------------------------------------------------------------
// FAST PATH (needs ~17 MB workspace)
// ---------------------------------------------------------------------------

// zero v + empty-row counters, fold masks into locs (invalid -> far sentinel;
// DIFFERENT sentinels per side so two invalid points are never "close").
__global__ __launch_bounds__(256) void prep_kernel(
    const float* __restrict__ sloc, const float* __restrict__ tloc,
    const int* __restrict__ sm, const int* __restrict__ tm,
    float* __restrict__ v, int* __restrict__ ecnt,
    float2* __restrict__ slm, float2* __restrict__ tlm)
{
  int i = blockIdx.x * 256 + threadIdx.x;
  if (i < BB * NN) {
    v[i] = 0.0f;
    float2 s = ((const float2*)sloc)[i];
    slm[i] = sm[i] ? s : make_float2(1.0e9f, 1.0e9f);
    float2 t = ((const float2*)tloc)[i];
    tlm[i] = tm[i] ? t : make_float2(3.0e9f, 3.0e9f);
    if (i < BB) ecnt[i] = 0;
  }
}

// Row-side neighbor sweep -> permuted bitmap. 4 waves/block, 4 rows/wave
// (16 rows/block), 1024 blocks. Lane L, iter i tests partners i*128+2L and
// i*128+2L+1 (one float4). Bit k of lane L's word <=> partner
// n = (k>>1)*128 + 2L + (k&1); bits accumulate via right-shift.
__global__ __launch_bounds__(256) void sweep8_kernel(
    const float2* __restrict__ slm, const float2* __restrict__ tlm,
    unsigned long long* __restrict__ row_bm,
    int* __restrict__ ecnt)
{
  constexpr int RPB = 16;                 // rows per block
  const int  rbase  = blockIdx.x * RPB;
  const int  b      = rbase >> 12;        // 4096 % 16 == 0: no batch straddle
  const int  lane   = threadIdx.x & 63;
  const int  wid    = threadIdx.x >> 6;
  const int  row0   = rbase + wid * 4;

  const float2 a0 = tlm[row0 + 0];
  const float2 a1 = tlm[row0 + 1];
  const float2 a2 = tlm[row0 + 2];
  const float2 a3 = tlm[row0 + 3];
  const float4* __restrict__ bl4 = (const float4*)(slm + (size_t)b * 4096);

  unsigned long long w0 = 0, w1 = 0, w2 = 0, w3 = 0;
#pragma unroll 8
  for (int i = 0; i < 32; ++i) {
    float4 q = bl4[i * 64 + lane];
#define SWTEST(aa, ww)                                             \
    do {                                                           \
      float dx0 = (aa).x - q.x, dy0 = (aa).y - q.y;                \
      float dx1 = (aa).x - q.z, dy1 = (aa).y - q.w;                \
      bool p0 = fmaf(dy0, dy0, dx0 * dx0) < kThresh2;              \
      bool p1 = fmaf(dy1, dy1, dx1 * dx1) < kThresh2;              \
      ww = (ww >> 2) | (p0 ? (1ull << 62) : 0ull)                  \
                     | (p1 ? (1ull << 63) : 0ull);                 \
    } while (0)
    SWTEST(a0, w0);
    SWTEST(a1, w1);
    SWTEST(a2, w2);
    SWTEST(a3, w3);
#undef SWTEST
  }

  row_bm[(size_t)(row0 + 0) * 64 + lane] = w0;
  row_bm[(size_t)(row0 + 1) * 64 + lane] = w1;
  row_bm[(size_t)(row0 + 2) * 64 + lane] = w2;
  row_bm[(size_t)(row0 + 3) * 64 + lane] = w3;

  // empty-row census for the contamination count cc
  unsigned long long z0 = __ballot(w0 != 0ull);
  unsigned long long z1 = __ballot(w1 != 0ull);
  unsigned long long z2 = __ballot(w2 != 0ull);
  unsigned long long z3 = __ballot(w3 != 0ull);
  if (lane == 0) {
    int e = (z0 == 0ull) + (z1 == 0ull) + (z2 == 0ull) + (z3 == 0ull);
    if (e) atomicAdd(&ecnt[b], e);
  }
}

// col_bm = bit-transpose of row_bm. One block per (batch b, L'): stages the
// 64 rows {m_rho = (rho>>1)*128 + 2L' + (rho&1)} x 64 words coalesced into
// LDS (rotated slot (L+rho)&63 -> 4-way conflict on column reads), then each
// wave transposes 16 of the 64 column-tiles with a 6-step shfl_xor butterfly
// and scatter-stores the resulting col words.
__global__ __launch_bounds__(256) void bt_kernel(
    const unsigned long long* __restrict__ row_bm,
    unsigned long long* __restrict__ col_bm)
{
  __shared__ unsigned long long tile[64 * 64];   // 32 KB

  const int b    = blockIdx.x >> 6;
  const int Lp   = blockIdx.x & 63;              // L'
  const int tid  = threadIdx.x;
  const int lane = tid & 63;
  const int wid  = tid >> 6;

  const unsigned long long* __restrict__ rb =
      row_bm + ((size_t)b << 12) * 64;
  unsigned long long* __restrict__ cb =
      col_bm + ((size_t)b << 12) * 64;

#pragma unroll
  for (int r = 0; r < 16; ++r) {
    int q   = r * 256 + tid;                     // [0, 4096)
    int rho = q >> 6, L = q & 63;
    int m   = ((rho >> 1) << 7) + 2 * Lp + (rho & 1);
    tile[rho * 64 + ((L + rho) & 63)] = rb[(size_t)m * 64 + L];
  }
  __syncthreads();

  for (int i = 0; i < 16; ++i) {
    const int Lt = wid * 16 + i;                 // L (col-side word owner)
    unsigned long long w = tile[lane * 64 + ((Lt + lane) & 63)];
    // butterfly: swap off-diagonal s x s blocks between lanes lam and lam^s
#define BTSTEP(S, MLO)                                                  \
    do {                                                                \
      unsigned long long t = __shfl_xor(w, S, 64);                      \
      w = (lane & S) ? ((w & ~(MLO)) | ((t >> S) & (MLO)))              \
                     : ((w & (MLO)) | ((t & (MLO)) << S));              \
    } while (0)
    BTSTEP(32, 0x00000000FFFFFFFFull);
    BTSTEP(16, 0x0000FFFF0000FFFFull);
    BTSTEP(8,  0x00FF00FF00FF00FFull);
    BTSTEP(4,  0x0F0F0F0F0F0F0F0Full);
    BTSTEP(2,  0x3333333333333333ull);
    BTSTEP(1,  0x5555555555555555ull);
#undef BTSTEP
    const int n = ((lane >> 1) << 7) + 2 * Lt + (lane & 1);
    cb[(size_t)n * 64 + Lp] = w;
  }
}

// u[row] = -log(sum_j exp(logK_j + v[n_j])), +1e9 if no valid entries.
// One wave per row; lane L ctz-enumerates its own bitmap word. No max pass:
// all t bounded (|t| << 87), exp cannot over/underflow.
__global__ __launch_bounds__(256) void lse_row_kernel(
    const float2* __restrict__ tlm, const float2* __restrict__ slm,
    const unsigned long long* __restrict__ row_bm,
    const float* __restrict__ v, float* __restrict__ u)
{
  const int lane = threadIdx.x & 63;
  const int row  = blockIdx.x * 4 + (threadIdx.x >> 6);
  const int b    = row >> 12;
  unsigned long long w = row_bm[(size_t)row * 64 + lane];
  const float2 a = tlm[row];
  const float2* __restrict__ sl = slm + (size_t)b * NN;
  const float*  __restrict__ vb = v + (size_t)b * NN;
  float s_l = 0.0f;
  while (w) {
    int k = (int)__builtin_ctzll(w);
    w &= w - 1;
    int n = ((k >> 1) << 7) + 2 * lane + (k & 1);
    float2 s = sl[n];
    float dx = a.x - s.x, dy = a.y - s.y;
    float t = fmaf(dy, dy, dx * dx) * kNegInvEps + vb[n];
    s_l += __expf(t);
  }
  float ssum = wave_reduce_sum(s_l);
  if (lane == 0) u[row] = (ssum == 0.0f) ? 1.0e9f : -__logf(ssum);
}

// v[col] = !sv ? 0 : -log(sum exp(t) + cc); +1e9 if both empty.
__global__ __launch_bounds__(256) void lse_col_kernel(
    const float2* __restrict__ slm, const float2* __restrict__ tlm,
    const unsigned long long* __restrict__ col_bm,
    const int* __restrict__ smask, const int* __restrict__ ecnt,
    const float* __restrict__ u, float* __restrict__ v)
{
  const int lane = threadIdx.x & 63;
  const int col  = blockIdx.x * 4 + (threadIdx.x >> 6);
  if (!smask[col]) { if (lane == 0) v[col] = 0.0f; return; }
  const int b = col >> 12;
  unsigned long long w = col_bm[(size_t)col * 64 + lane];
  const float2 a = slm[col];
  const float2* __restrict__ tl = tlm + (size_t)b * MM;
  const float*  __restrict__ ub = u + (size_t)b * MM;
  float s_l = 0.0f;
  while (w) {
    int k = (int)__builtin_ctzll(w);
    w &= w - 1;
    int m = ((k >> 1) << 7) + 2 * lane + (k & 1);
    float2 s = tl[m];
    float dx = a.x - s.x, dy = a.y - s.y;
    float t = fmaf(dy, dy, dx * dx) * kNegInvEps + ub[m];
    s_l += __expf(t);
  }
  float ssum = wave_reduce_sum(s_l);
  if (lane == 0) {
    float tot = ssum + (float)ecnt[b];   // contamination entries are exp(0)=1
    v[col] = (tot == 0.0f) ? 1.0e9f : -__logf(tot);
  }
}

// out[row,:] = sum_j attn_j * feats[n_j,:], one block per row.
// XCD-affine swizzle: row = (xcd>>1)*4096 + slot*2 + (xcd&1) so each XCD's
// L2 caches only its own batch's 2MB of feats.
// Phase 1: 256 threads extract the row's bitmap (thread t owns the
// (t&3)-th 16-bit quarter of word t>>2), compute attn, append to LDS via
// atomic slot. Phase 2: 8 groups x 32 lanes gather feats float4.
__global__ __launch_bounds__(256) void output3_kernel(
    const float2* __restrict__ tlm, const float2* __restrict__ slm,
    const unsigned long long* __restrict__ row_bm,
    const float* __restrict__ u, const float* __restrict__ v,
    const float* __restrict__ feats, float* __restrict__ out)
{
  __shared__ float s_attn[1024];
  __shared__ unsigned short s_id[1024];
  __shared__ float4 s_red[256];
  __shared__ int s_cnt;

  const int xcd  = blockIdx.x & 7;
  const int slot = blockIdx.x >> 3;
  const int row  = ((xcd >> 1) << 12) + slot * 2 + (xcd & 1);
  const int tid = threadIdx.x;
  const int b   = row >> 12;
  if (tid == 0) s_cnt = 0;
  __syncthreads();

  {
    const int L  = tid >> 2;
    const int qp = tid & 3;
    unsigned long long w = row_bm[(size_t)row * 64 + L];
    unsigned wq = (unsigned)(unsigned short)(w >> (qp * 16));
    if (wq) {
      const float um = u[row];
      const float2 a = tlm[row];
      const float2* __restrict__ sl = slm + (size_t)b * NN;
      const float*  __restrict__ vb = v + (size_t)b * NN;
      while (wq) {
        int kk = (int)__builtin_ctz(wq);
        wq &= wq - 1;
        int k = qp * 16 + kk;
        int n = ((k >> 1) << 7) + 2 * L + (k & 1);
        float2 s = sl[n];
        float dx = a.x - s.x, dy = a.y - s.y;
        float aw = __expf(fmaf(dy, dy, dx * dx) * kNegInvEps + um + vb[n]);
        int p = atomicAdd(&s_cnt, 1);
        if (p < 1024) { s_attn[p] = aw; s_id[p] = (unsigned short)n; }
      }
    }
  }
  __syncthreads();

  int cnt = s_cnt;
  if (cnt > 1024) cnt = 1024;             // realistic max ~330, never hit
  float4* op = (float4*)(out + (size_t)row * CC);
  if (cnt == 0) {                         // covers !tgt_valid and !has_source
    if (tid < 32) op[tid] = make_float4(0.f, 0.f, 0.f, 0.f);
    return;
  }

  const int g = tid >> 5, l = tid & 31;
  const float4* __restrict__ fb = (const float4*)(feats + (size_t)b * NN * CC);
  float4 acc = make_float4(0.f, 0.f, 0.f, 0.f);
  for (int j = g; j < cnt; j += 8) {
    float aw = s_attn[j];
    int   n  = s_id[j];
    float4 f = fb[(size_t)n * 32 + l];
    acc.x = fmaf(aw, f.x, acc.x);
    acc.y = fmaf(aw, f.y, acc.y);
    acc.z = fmaf(aw, f.z, acc.z);
    acc.w = fmaf(aw, f.w, acc.w);
  }
  s_red[tid] = acc;
  __syncthreads();
  if (tid < 32) {
    float4 r = s_red[tid];
#pragma unroll
    for (int gg = 1; gg < 8; ++gg) {
      float4 p = s_red[gg * 32 + tid];
      r.x += p.x; r.y += p.y; r.z += p.z; r.w += p.w;
    }
    op[tid] = r;
  }
}

// ---------------------------------------------------------------------------
// FALLBACK PATH (round-1 kernels, ~128 KB workspace) — used if ws too small
// ---------------------------------------------------------------------------

__global__ __launch_bounds__(256) void init_v_kernel(float* __restrict__ v) {
  int i = blockIdx.x * 256 + threadIdx.x;
  if (i < BB * NN) v[i] = 0.0f;
}

__global__ __launch_bounds__(256) void u_update_kernel(
    const float* __restrict__ src_locs, const float* __restrict__ tgt_locs,
    const int* __restrict__ src_valid, const int* __restrict__ tgt_valid,
    const float* __restrict__ v, float* __restrict__ u)
{
  const int lane = threadIdx.x & 63;
  const int row  = blockIdx.x * 4 + (threadIdx.x >> 6);
  const int b    = row / MM;
  const float tx = tgt_locs[row * 2 + 0];
  const float ty = tgt_locs[row * 2 + 1];
  const bool  tv = tgt_valid[row] != 0;
  const float2* __restrict__ sl  = (const float2*)(src_locs + (size_t)b * NN * 2);
  const float*  __restrict__ vb  = v + (size_t)b * NN;
  const int*    __restrict__ svb = src_valid + (size_t)b * NN;
  float mx = -3.0e38f;
#pragma unroll 4
  for (int i = 0; i < NN / 64; ++i) {
    int n = i * 64 + lane;
    float2 s = sl[n];
    float dx = tx - s.x, dy = ty - s.y;
    float d2 = dx * dx + dy * dy;
    bool valid = (d2 < kThresh2) & tv & (svb[n] != 0);
    float t = (valid ? d2 * kNegInvEps : kNegInf) + vb[n];
    mx = fmaxf(mx, t);
  }
  mx = wave_reduce_max(mx);
  float s = 0.0f;
#pragma unroll 4
  for (int i = 0; i < NN / 64; ++i) {
    int n = i * 64 + lane;
    float2 sc = sl[n];
    float dx = tx - sc.x, dy = ty - sc.y;
    float d2 = dx * dx + dy * dy;
    bool valid = (d2 < kThresh2) & tv & (svb[n] != 0);
    float t = (valid ? d2 * kNegInvEps : kNegInf) + vb[n];
    s += __expf(t - mx);
  }
  s = wave_reduce_sum(s);
  if (lane == 0) u[row] = -(mx + __logf(s));
}

__global__ __launch_bounds__(256) void v_update_kernel(
    const float* __restrict__ src_locs, const float* __restrict__ tgt_locs,
    const int* __restrict__ src_valid, const int* __restrict__ tgt_valid,
    const float* __restrict__ u, float* __restrict__ v)
{
  const int lane = threadIdx.x & 63;
  const int col  = blockIdx.x * 4 + (threadIdx.x >> 6);
  const int b    = col / NN;
  const float sx = src_locs[col * 2 + 0];
  const float sy = src_locs[col * 2 + 1];
  const bool  sv = src_valid[col] != 0;
  const float2* __restrict__ tl  = (const float2*)(tgt_locs + (size_t)b * MM * 2);
  const float*  __restrict__ ub  = u + (size_t)b * MM;
  const int*    __restrict__ tvb = tgt_valid + (size_t)b * MM;
  float mx = -3.0e38f;
#pragma unroll 4
  for (int i = 0; i < MM / 64; ++i) {
    int m = i * 64 + lane;
    float2 t2 = tl[m];
    float dx = t2.x - sx, dy = t2.y - sy;
    float d2 = dx * dx + dy * dy;
    bool valid = (d2 < kThresh2) & sv & (tvb[m] != 0);
    float t = (valid ? d2 * kNegInvEps : kNegInf) + ub[m];
    mx = fmaxf(mx, t);
  }
  mx = wave_reduce_max(mx);
  float s = 0.0f;
#pragma unroll 4
  for (int i = 0; i < MM / 64; ++i) {
    int m = i * 64 + lane;
    float2 t2 = tl[m];
    float dx = t2.x - sx, dy = t2.y - sy;
    float d2 = dx * dx + dy * dy;
    bool valid = (d2 < kThresh2) & sv & (tvb[m] != 0);
    float t = (valid ? d2 * kNegInvEps : kNegInf) + ub[m];
    s += __expf(t - mx);
  }
  s = wave_reduce_sum(s);
  if (lane == 0) v[col] = sv ? -(mx + __logf(s)) : 0.0f;
}

__global__ __launch_bounds__(256) void output_kernel(
    const float* __restrict__ src_locs, const float* __restrict__ tgt_locs,
    const int* __restrict__ src_valid, const int* __restrict__ tgt_valid,
    const float* __restrict__ u, const float* __restrict__ v,
    const float* __restrict__ feats, float* __restrict__ out)
{
  __shared__ float s_attn[NN];
  __shared__ int   s_idx[NN];
  __shared__ int   s_cnt;
  __shared__ float s_part[CC];
  const int row = blockIdx.x;
  const int b   = row / MM;
  const int tid = threadIdx.x;
  if (tid == 0) s_cnt = 0;
  __syncthreads();
  const float tx = tgt_locs[row * 2 + 0];
  const float ty = tgt_locs[row * 2 + 1];
  const bool  tv = tgt_valid[row] != 0;
  const float um = u[row];
  const float2* __restrict__ sl  = (const float2*)(src_locs + (size_t)b * NN * 2);
  const float*  __restrict__ vb  = v + (size_t)b * NN;
  const int*    __restrict__ svb = src_valid + (size_t)b * NN;
#pragma unroll 4
  for (int i = 0; i < NN / 256; ++i) {
    int n = i * 256 + tid;
    float2 s = sl[n];
    float dx = tx - s.x, dy = ty - s.y;
    float d2 = dx * dx + dy * dy;
    bool valid = (d2 < kThresh2) & tv & (svb[n] != 0);
    if (valid) {
      float a = __expf((d2 * kNegInvEps + um) + vb[n]);
      int p = atomicAdd(&s_cnt, 1);
      s_attn[p] = a;
      s_idx[p]  = n;
    }
  }
  __syncthreads();
  const int cnt = s_cnt;
  const int g = tid >> 7;
  const int c = tid & (CC - 1);
  const float* __restrict__ fb = feats + (size_t)b * NN * CC;
  float acc = 0.0f;
  for (int j = g; j < cnt; j += 2) {
    float a = s_attn[j];
    int   n = s_idx[j];
    acc = fmaf(a, fb[(size_t)n * CC + c], acc);
  }
  if (g == 1) s_part[c] = acc;
  __syncthreads();
  if (g == 0) {
    float r = (cnt > 0) ? (acc + s_part[c]) : 0.0f;
    out[(size_t)row * CC + c] = r;
  }
}

// ---------------------------------------------------------------------------

extern "C" void kernel_launch(void* const* d_in, const int* in_sizes, int n_in,
                              void* d_out, int out_size, void* d_ws, size_t ws_size,
                              hipStream_t stream) {
  const float* feats = (const float*)d_in[0];
  const float* sloc  = (const float*)d_in[1];
  const float* tloc  = (const float*)d_in[2];
  const int*   smask = (const int*)d_in[3];
  const int*   tmask = (const int*)d_in[4];
  float* out = (float*)d_out;

  // workspace layout (fast path): ~17 MB
  char* p = (char*)d_ws;
  float* u_   = (float*)p;            p += (size_t)BB * MM * 4;
  float* v_   = (float*)p;            p += (size_t)BB * NN * 4;
  int* ecnt   = (int*)p;              p += 256;
  float2* slm = (float2*)p;           p += (size_t)BB * NN * 8;
  float2* tlm = (float2*)p;           p += (size_t)BB * MM * 8;
  unsigned long long* row_bm = (unsigned long long*)p; p += (size_t)BB * MM * 64 * 8;
  unsigned long long* col_bm = (unsigned long long*)p; p += (size_t)BB * NN * 64 * 8;
  size_t required = (size_t)(p - (char*)d_ws);

  if (ws_size >= required) {
    prep_kernel<<<(BB * NN + 255) / 256, 256, 0, stream>>>(
        sloc, tloc, smask, tmask, v_, ecnt, slm, tlm);
    sweep8_kernel<<<BB * MM / 16, 256, 0, stream>>>(
        slm, tlm, row_bm, ecnt);
    bt_kernel<<<BB * 64, 256, 0, stream>>>(row_bm, col_bm);
    for (int it = 0; it < 3; ++it) {
      lse_row_kernel<<<BB * MM / 4, 256, 0, stream>>>(tlm, slm, row_bm, v_, u_);
      lse_col_kernel<<<BB * NN / 4, 256, 0, stream>>>(slm, tlm, col_bm,
                                                      smask, ecnt, u_, v_);
    }
    output3_kernel<<<BB * MM, 256, 0, stream>>>(tlm, slm, row_bm,
                                                u_, v_, feats, out);
  } else {
    // fallback: round-1 path (dense re-sweeps), needs only 128 KB
    float* u = (float*)d_ws;
    float* v = u + (size_t)BB * MM;
    init_v_kernel<<<(BB * NN + 255) / 256, 256, 0, stream>>>(v);
    for (int it = 0; it < 3; ++it) {
      u_update_kernel<<<BB * MM / 4, 256, 0, stream>>>(sloc, tloc, smask, tmask, v, u);
      v_update_kernel<<<BB * NN / 4, 256, 0, stream>>>(sloc, tloc, smask, tmask, u, v);
    }
    output_kernel<<<BB * MM, 256, 0, stream>>>(sloc, tloc, smask, tmask, u, v, feats, out);
  }
}

// Round 7
// 241.093 us; speedup vs baseline: 1.0446x; 1.0446x over previous
//
#include <hip/hip_runtime.h>

// GeometryOptimalTransport: B=4, N=M=4096, C=128
// Sinkhorn (3 iters) over log_K(m,n) = -dist2/eps masked to -1e9, then
// attn-weighted gather of source feats.
//
// R2: validity is iteration-invariant -> precompute adjacency once; run all
// lse updates + output on the ~3% dense structure. Finite NEG_INF=-1e9
// contamination is closed-form:
//   - row with 0 valid entries => u = +1e9 EXACTLY (ulp(1e9)=64)
//   - such rows contribute exp(0) to EVERY column lse => per-batch count cc
//   - all other invalid entries underflow to exactly 0 in fp32.
// R5-R10 journal: compaction costs ~60us in ANY form -> permuted bitmap
// (bit k of lane L's word <=> partner n=(k>>1)*128+2L+(k&1)). Sweep time is
// invariant to load volume (R5), LDS staging (R8), compaction removal (R7),
// and block count (R9: half blocks, same ~60us) -> stall cause unidentified;
// only ~15us of it is VALU issue. col_bm = bit-transpose of row_bm via
// 6-step shfl_xor butterfly (R9, verified). output3 measured AT the L2
// roofline (1.9GB gathers / 55us = 35 TB/s) -> not improvable w/o precision
// loss or spatial sort.
// R11 (this round):
//   (a) fold u1 (first lse_row, v0=0) into the sweep: s += p ? exp(d2*c) : 0
//       per test + wave reduce; deletes one ~18us dispatch; extra VALU hides
//       in the sweep's stall shadow. ssum==0 <=> empty row drives ecnt.
//   (b) one consistent XCD-chunk affinity across sweep/lse/output: block j
//       -> rows [(j&7)*2048 ...), so XCD k owns the same 2048-row slice in
//       every kernel; bitmaps/locs/u/v stay in its 4MB L2 across all passes.

constexpr int   BB = 4;
constexpr int   NN = 4096;
constexpr int   MM = 4096;
constexpr int   CC = 128;
constexpr float kNegInf    = -1000000000.0f;
constexpr float kThresh2   = 0.04f;                 // 0.2^2
constexpr float kNegInvEps = -(1.0f / 0.01000001f); // -(1/(EPSILON+1e-8))

__device__ inline float wave_reduce_max(float x) {
#pragma unroll
  for (int off = 32; off > 0; off >>= 1)
    x = fmaxf(x, __shfl_xor(x, off, 64));
  return x;
}
__device__ inline float wave_reduce_sum(float x) {
#pragma unroll
  for (int off = 32; off > 0; off >>= 1)
    x += __shfl_xor(x, off, 64);
  return x;
}

// ---------------------------------------------------------------------------
// FAST PATH (needs ~17 MB workspace)
// ---------------------------------------------------------------------------

// zero v + empty-row counters, fold masks into locs (invalid -> far sentinel;
// DIFFERENT sentinels per side so two invalid points are never "close").
__global__ __launch_bounds__(256) void prep_kernel(
    const float* __restrict__ sloc, const float* __restrict__ tloc,
    const int* __restrict__ sm, const int* __restrict__ tm,
    float* __restrict__ v, int* __restrict__ ecnt,
    float2* __restrict__ slm, float2* __restrict__ tlm)
{
  int i = blockIdx.x * 256 + threadIdx.x;
  if (i < BB * NN) {
    v[i] = 0.0f;
    float2 s = ((const float2*)sloc)[i];
    slm[i] = sm[i] ? s : make_float2(1.0e9f, 1.0e9f);
    float2 t = ((const float2*)tloc)[i];
    tlm[i] = tm[i] ? t : make_float2(3.0e9f, 3.0e9f);
    if (i < BB) ecnt[i] = 0;
  }
}

// Row-side neighbor sweep -> permuted bitmap + FUSED u1 (first lse_row with
// v0=0). 4 waves/block, 4 rows/wave (16 rows/block), 1024 blocks.
// XCD-chunk affinity: block j -> rows (j&7)*2048 + (j>>3)*16 ... +15.
// Lane L, iter i tests partners i*128+2L and i*128+2L+1 (one float4).
// Bit k of lane L's word <=> partner n = (k>>1)*128 + 2L + (k&1).
__global__ __launch_bounds__(256) void sweep9_kernel(
    const float2* __restrict__ slm, const float2* __restrict__ tlm,
    unsigned long long* __restrict__ row_bm,
    int* __restrict__ ecnt, float* __restrict__ u)
{
  constexpr int RPB = 16;                 // rows per block
  const int  j      = blockIdx.x;
  const int  rbase  = (j & 7) * 2048 + (j >> 3) * RPB;  // chunk-affine
  const int  b      = rbase >> 12;        // chunks (2048 rows) never straddle
  const int  lane   = threadIdx.x & 63;
  const int  wid    = threadIdx.x >> 6;
  const int  row0   = rbase + wid * 4;

  const float2 a0 = tlm[row0 + 0];
  const float2 a1 = tlm[row0 + 1];
  const float2 a2 = tlm[row0 + 2];
  const float2 a3 = tlm[row0 + 3];
  const float4* __restrict__ bl4 = (const float4*)(slm + (size_t)b * 4096);

  unsigned long long w0 = 0, w1 = 0, w2 = 0, w3 = 0;
  float s0 = 0.0f, s1 = 0.0f, s2 = 0.0f, s3 = 0.0f;
#pragma unroll 8
  for (int i = 0; i < 32; ++i) {
    float4 q = bl4[i * 64 + lane];
#define SWTEST(aa, ww, ss)                                         \
    do {                                                           \
      float dx0 = (aa).x - q.x, dy0 = (aa).y - q.y;                \
      float dx1 = (aa).x - q.z, dy1 = (aa).y - q.w;                \
      float d0 = fmaf(dy0, dy0, dx0 * dx0);                        \
      float d1 = fmaf(dy1, dy1, dx1 * dx1);                        \
      bool p0 = d0 < kThresh2;                                     \
      bool p1 = d1 < kThresh2;                                     \
      ww = (ww >> 2) | (p0 ? (1ull << 62) : 0ull)                  \
                     | (p1 ? (1ull << 63) : 0ull);                 \
      float e0 = __expf(d0 * kNegInvEps);                          \
      float e1 = __expf(d1 * kNegInvEps);                          \
      ss += p0 ? e0 : 0.0f;                                        \
      ss += p1 ? e1 : 0.0f;                                        \
    } while (0)
    SWTEST(a0, w0, s0);
    SWTEST(a1, w1, s1);
    SWTEST(a2, w2, s2);
    SWTEST(a3, w3, s3);
#undef SWTEST
  }

  row_bm[(size_t)(row0 + 0) * 64 + lane] = w0;
  row_bm[(size_t)(row0 + 1) * 64 + lane] = w1;
  row_bm[(size_t)(row0 + 2) * 64 + lane] = w2;
  row_bm[(size_t)(row0 + 3) * 64 + lane] = w3;

  // u1 = -log(ssum) per row (v0 = 0); ssum==0 <=> empty row (valid terms are
  // exp(t), t >= -4, so a non-empty row's sum cannot underflow).
  s0 = wave_reduce_sum(s0);
  s1 = wave_reduce_sum(s1);
  s2 = wave_reduce_sum(s2);
  s3 = wave_reduce_sum(s3);
  if (lane == 0) {
    u[row0 + 0] = (s0 == 0.0f) ? 1.0e9f : -__logf(s0);
    u[row0 + 1] = (s1 == 0.0f) ? 1.0e9f : -__logf(s1);
    u[row0 + 2] = (s2 == 0.0f) ? 1.0e9f : -__logf(s2);
    u[row0 + 3] = (s3 == 0.0f) ? 1.0e9f : -__logf(s3);
    int e = (s0 == 0.0f) + (s1 == 0.0f) + (s2 == 0.0f) + (s3 == 0.0f);
    if (e) atomicAdd(&ecnt[b], e);
  }
}

// col_bm = bit-transpose of row_bm. One block per (batch b, L'): stages the
// 64 rows {m_rho = (rho>>1)*128 + 2L' + (rho&1)} x 64 words coalesced into
// LDS (rotated slot (L+rho)&63 -> 4-way conflict on column reads), then each
// wave transposes 16 of the 64 column-tiles with a 6-step shfl_xor butterfly
// and scatter-stores the resulting col words.
__global__ __launch_bounds__(256) void bt_kernel(
    const unsigned long long* __restrict__ row_bm,
    unsigned long long* __restrict__ col_bm)
{
  __shared__ unsigned long long tile[64 * 64];   // 32 KB

  const int b    = blockIdx.x >> 6;
  const int Lp   = blockIdx.x & 63;              // L'
  const int tid  = threadIdx.x;
  const int lane = tid & 63;
  const int wid  = tid >> 6;

  const unsigned long long* __restrict__ rb =
      row_bm + ((size_t)b << 12) * 64;
  unsigned long long* __restrict__ cb =
      col_bm + ((size_t)b << 12) * 64;

#pragma unroll
  for (int r = 0; r < 16; ++r) {
    int q   = r * 256 + tid;                     // [0, 4096)
    int rho = q >> 6, L = q & 63;
    int m   = ((rho >> 1) << 7) + 2 * Lp + (rho & 1);
    tile[rho * 64 + ((L + rho) & 63)] = rb[(size_t)m * 64 + L];
  }
  __syncthreads();

  for (int i = 0; i < 16; ++i) {
    const int Lt = wid * 16 + i;                 // L (col-side word owner)
    unsigned long long w = tile[lane * 64 + ((Lt + lane) & 63)];
    // butterfly: swap off-diagonal s x s blocks between lanes lam and lam^s
#define BTSTEP(S, MLO)                                                  \
    do {                                                                \
      unsigned long long t = __shfl_xor(w, S, 64);                      \
      w = (lane & S) ? ((w & ~(MLO)) | ((t >> S) & (MLO)))              \
                     : ((w & (MLO)) | ((t & (MLO)) << S));              \
    } while (0)
    BTSTEP(32, 0x00000000FFFFFFFFull);
    BTSTEP(16, 0x0000FFFF0000FFFFull);
    BTSTEP(8,  0x00FF00FF00FF00FFull);
    BTSTEP(4,  0x0F0F0F0F0F0F0F0Full);
    BTSTEP(2,  0x3333333333333333ull);
    BTSTEP(1,  0x5555555555555555ull);
#undef BTSTEP
    const int n = ((lane >> 1) << 7) + 2 * Lt + (lane & 1);
    cb[(size_t)n * 64 + Lp] = w;
  }
}

// u[row] = -log(sum_j exp(logK_j + v[n_j])), +1e9 if no valid entries.
// One wave per row, chunk-affine (block j -> rows (j&7)*2048 + (j>>3)*4).
// Lane L ctz-enumerates its own bitmap word. No max pass: all t bounded
// (|t| << 87), exp cannot over/underflow.
__global__ __launch_bounds__(256) void lse_row_kernel(
    const float2* __restrict__ tlm, const float2* __restrict__ slm,
    const unsigned long long* __restrict__ row_bm,
    const float* __restrict__ v, float* __restrict__ u)
{
  const int lane = threadIdx.x & 63;
  const int j    = blockIdx.x;
  const int row  = (j & 7) * 2048 + (j >> 3) * 4 + (threadIdx.x >> 6);
  const int b    = row >> 12;
  unsigned long long w = row_bm[(size_t)row * 64 + lane];
  const float2 a = tlm[row];
  const float2* __restrict__ sl = slm + (size_t)b * NN;
  const float*  __restrict__ vb = v + (size_t)b * NN;
  float s_l = 0.0f;
  while (w) {
    int k = (int)__builtin_ctzll(w);
    w &= w - 1;
    int n = ((k >> 1) << 7) + 2 * lane + (k & 1);
    float2 s = sl[n];
    float dx = a.x - s.x, dy = a.y - s.y;
    float t = fmaf(dy, dy, dx * dx) * kNegInvEps + vb[n];
    s_l += __expf(t);
  }
  float ssum = wave_reduce_sum(s_l);
  if (lane == 0) u[row] = (ssum == 0.0f) ? 1.0e9f : -__logf(ssum);
}

// v[col] = !sv ? 0 : -log(sum exp(t) + cc); +1e9 if both empty.
// Chunk-affine like lse_row.
__global__ __launch_bounds__(256) void lse_col_kernel(
    const float2* __restrict__ slm, const float2* __restrict__ tlm,
    const unsigned long long* __restrict__ col_bm,
    const int* __restrict__ smask, const int* __restrict__ ecnt,
    const float* __restrict__ u, float* __restrict__ v)
{
  const int lane = threadIdx.x & 63;
  const int j    = blockIdx.x;
  const int col  = (j & 7) * 2048 + (j >> 3) * 4 + (threadIdx.x >> 6);
  if (!smask[col]) { if (lane == 0) v[col] = 0.0f; return; }
  const int b = col >> 12;
  unsigned long long w = col_bm[(size_t)col * 64 + lane];
  const float2 a = slm[col];
  const float2* __restrict__ tl = tlm + (size_t)b * MM;
  const float*  __restrict__ ub = u + (size_t)b * MM;
  float s_l = 0.0f;
  while (w) {
    int k = (int)__builtin_ctzll(w);
    w &= w - 1;
    int m = ((k >> 1) << 7) + 2 * lane + (k & 1);
    float2 s = tl[m];
    float dx = a.x - s.x, dy = a.y - s.y;
    float t = fmaf(dy, dy, dx * dx) * kNegInvEps + ub[m];
    s_l += __expf(t);
  }
  float ssum = wave_reduce_sum(s_l);
  if (lane == 0) {
    float tot = ssum + (float)ecnt[b];   // contamination entries are exp(0)=1
    v[col] = (tot == 0.0f) ? 1.0e9f : -__logf(tot);
  }
}

// out[row,:] = sum_j attn_j * feats[n_j,:], one block per row, chunk-affine
// (block j -> row (j&7)*2048 + (j>>3); same slice per XCD as all other
// kernels, so each XCD's L2 holds its own batch-half's feats + bitmaps).
// Phase 1: 256 threads extract the row's bitmap (thread t owns the
// (t&3)-th 16-bit quarter of word t>>2), compute attn, append to LDS via
// atomic slot. Phase 2: 8 groups x 32 lanes gather feats float4.
// (measured at L2 roofline: ~1.9GB of gathers / 55us = 35 TB/s)
__global__ __launch_bounds__(256) void output3_kernel(
    const float2* __restrict__ tlm, const float2* __restrict__ slm,
    const unsigned long long* __restrict__ row_bm,
    const float* __restrict__ u, const float* __restrict__ v,
    const float* __restrict__ feats, float* __restrict__ out)
{
  __shared__ float s_attn[1024];
  __shared__ unsigned short s_id[1024];
  __shared__ float4 s_red[256];
  __shared__ int s_cnt;

  const int j   = blockIdx.x;
  const int row = (j & 7) * 2048 + (j >> 3);
  const int tid = threadIdx.x;
  const int b   = row >> 12;
  if (tid == 0) s_cnt = 0;
  __syncthreads();

  {
    const int L  = tid >> 2;
    const int qp = tid & 3;
    unsigned long long w = row_bm[(size_t)row * 64 + L];
    unsigned wq = (unsigned)(unsigned short)(w >> (qp * 16));
    if (wq) {
      const float um = u[row];
      const float2 a = tlm[row];
      const float2* __restrict__ sl = slm + (size_t)b * NN;
      const float*  __restrict__ vb = v + (size_t)b * NN;
      while (wq) {
        int kk = (int)__builtin_ctz(wq);
        wq &= wq - 1;
        int k = qp * 16 + kk;
        int n = ((k >> 1) << 7) + 2 * L + (k & 1);
        float2 s = sl[n];
        float dx = a.x - s.x, dy = a.y - s.y;
        float aw = __expf(fmaf(dy, dy, dx * dx) * kNegInvEps + um + vb[n]);
        int p = atomicAdd(&s_cnt, 1);
        if (p < 1024) { s_attn[p] = aw; s_id[p] = (unsigned short)n; }
      }
    }
  }
  __syncthreads();

  int cnt = s_cnt;
  if (cnt > 1024) cnt = 1024;             // realistic max ~330, never hit
  float4* op = (float4*)(out + (size_t)row * CC);
  if (cnt == 0) {                         // covers !tgt_valid and !has_source
    if (tid < 32) op[tid] = make_float4(0.f, 0.f, 0.f, 0.f);
    return;
  }

  const int g = tid >> 5, l = tid & 31;
  const float4* __restrict__ fb = (const float4*)(feats + (size_t)b * NN * CC);
  float4 acc = make_float4(0.f, 0.f, 0.f, 0.f);
  for (int jj = g; jj < cnt; jj += 8) {
    float aw = s_attn[jj];
    int   n  = s_id[jj];
    float4 f = fb[(size_t)n * 32 + l];
    acc.x = fmaf(aw, f.x, acc.x);
    acc.y = fmaf(aw, f.y, acc.y);
    acc.z = fmaf(aw, f.z, acc.z);
    acc.w = fmaf(aw, f.w, acc.w);
  }
  s_red[tid] = acc;
  __syncthreads();
  if (tid < 32) {
    float4 r = s_red[tid];
#pragma unroll
    for (int gg = 1; gg < 8; ++gg) {
      float4 p = s_red[gg * 32 + tid];
      r.x += p.x; r.y += p.y; r.z += p.z; r.w += p.w;
    }
    op[tid] = r;
  }
}

// ---------------------------------------------------------------------------
// FALLBACK PATH (round-1 kernels, ~128 KB workspace) — used if ws too small
// ---------------------------------------------------------------------------

__global__ __launch_bounds__(256) void init_v_kernel(float* __restrict__ v) {
  int i = blockIdx.x * 256 + threadIdx.x;
  if (i < BB * NN) v[i] = 0.0f;
}

__global__ __launch_bounds__(256) void u_update_kernel(
    const float* __restrict__ src_locs, const float* __restrict__ tgt_locs,
    const int* __restrict__ src_valid, const int* __restrict__ tgt_valid,
    const float* __restrict__ v, float* __restrict__ u)
{
  const int lane = threadIdx.x & 63;
  const int row  = blockIdx.x * 4 + (threadIdx.x >> 6);
  const int b    = row / MM;
  const float tx = tgt_locs[row * 2 + 0];
  const float ty = tgt_locs[row * 2 + 1];
  const bool  tv = tgt_valid[row] != 0;
  const float2* __restrict__ sl  = (const float2*)(src_locs + (size_t)b * NN * 2);
  const float*  __restrict__ vb  = v + (size_t)b * NN;
  const int*    __restrict__ svb = src_valid + (size_t)b * NN;
  float mx = -3.0e38f;
#pragma unroll 4
  for (int i = 0; i < NN / 64; ++i) {
    int n = i * 64 + lane;
    float2 s = sl[n];
    float dx = tx - s.x, dy = ty - s.y;
    float d2 = dx * dx + dy * dy;
    bool valid = (d2 < kThresh2) & tv & (svb[n] != 0);
    float t = (valid ? d2 * kNegInvEps : kNegInf) + vb[n];
    mx = fmaxf(mx, t);
  }
  mx = wave_reduce_max(mx);
  float s = 0.0f;
#pragma unroll 4
  for (int i = 0; i < NN / 64; ++i) {
    int n = i * 64 + lane;
    float2 sc = sl[n];
    float dx = tx - sc.x, dy = ty - sc.y;
    float d2 = dx * dx + dy * dy;
    bool valid = (d2 < kThresh2) & tv & (svb[n] != 0);
    float t = (valid ? d2 * kNegInvEps : kNegInf) + vb[n];
    s += __expf(t - mx);
  }
  s = wave_reduce_sum(s);
  if (lane == 0) u[row] = -(mx + __logf(s));
}

__global__ __launch_bounds__(256) void v_update_kernel(
    const float* __restrict__ src_locs, const float* __restrict__ tgt_locs,
    const int* __restrict__ src_valid, const int* __restrict__ tgt_valid,
    const float* __restrict__ u, float* __restrict__ v)
{
  const int lane = threadIdx.x & 63;
  const int col  = blockIdx.x * 4 + (threadIdx.x >> 6);
  const int b    = col / NN;
  const float sx = src_locs[col * 2 + 0];
  const float sy = src_locs[col * 2 + 1];
  const bool  sv = src_valid[col] != 0;
  const float2* __restrict__ tl  = (const float2*)(tgt_locs + (size_t)b * MM * 2);
  const float*  __restrict__ ub  = u + (size_t)b * MM;
  const int*    __restrict__ tvb = tgt_valid + (size_t)b * MM;
  float mx = -3.0e38f;
#pragma unroll 4
  for (int i = 0; i < MM / 64; ++i) {
    int m = i * 64 + lane;
    float2 t2 = tl[m];
    float dx = t2.x - sx, dy = t2.y - sy;
    float d2 = dx * dx + dy * dy;
    bool valid = (d2 < kThresh2) & sv & (tvb[m] != 0);
    float t = (valid ? d2 * kNegInvEps : kNegInf) + ub[m];
    mx = fmaxf(mx, t);
  }
  mx = wave_reduce_max(mx);
  float s = 0.0f;
#pragma unroll 4
  for (int i = 0; i < MM / 64; ++i) {
    int m = i * 64 + lane;
    float2 t2 = tl[m];
    float dx = t2.x - sx, dy = t2.y - sy;
    float d2 = dx * dx + dy * dy;
    bool valid = (d2 < kThresh2) & sv & (tvb[m] != 0);
    float t = (valid ? d2 * kNegInvEps : kNegInf) + ub[m];
    s += __expf(t - mx);
  }
  s = wave_reduce_sum(s);
  if (lane == 0) v[col] = sv ? -(mx + __logf(s)) : 0.0f;
}

__global__ __launch_bounds__(256) void output_kernel(
    const float* __restrict__ src_locs, const float* __restrict__ tgt_locs,
    const int* __restrict__ src_valid, const int* __restrict__ tgt_valid,
    const float* __restrict__ u, const float* __restrict__ v,
    const float* __restrict__ feats, float* __restrict__ out)
{
  __shared__ float s_attn[NN];
  __shared__ int   s_idx[NN];
  __shared__ int   s_cnt;
  __shared__ float s_part[CC];
  const int row = blockIdx.x;
  const int b   = row / MM;
  const int tid = threadIdx.x;
  if (tid == 0) s_cnt = 0;
  __syncthreads();
  const float tx = tgt_locs[row * 2 + 0];
  const float ty = tgt_locs[row * 2 + 1];
  const bool  tv = tgt_valid[row] != 0;
  const float um = u[row];
  const float2* __restrict__ sl  = (const float2*)(src_locs + (size_t)b * NN * 2);
  const float*  __restrict__ vb  = v + (size_t)b * NN;
  const int*    __restrict__ svb = src_valid + (size_t)b * NN;
#pragma unroll 4
  for (int i = 0; i < NN / 256; ++i) {
    int n = i * 256 + tid;
    float2 s = sl[n];
    float dx = tx - s.x, dy = ty - s.y;
    float d2 = dx * dx + dy * dy;
    bool valid = (d2 < kThresh2) & tv & (svb[n] != 0);
    if (valid) {
      float a = __expf((d2 * kNegInvEps + um) + vb[n]);
      int p = atomicAdd(&s_cnt, 1);
      s_attn[p] = a;
      s_idx[p]  = n;
    }
  }
  __syncthreads();
  const int cnt = s_cnt;
  const int g = tid >> 7;
  const int c = tid & (CC - 1);
  const float* __restrict__ fb = feats + (size_t)b * NN * CC;
  float acc = 0.0f;
  for (int j = g; j < cnt; j += 2) {
    float a = s_attn[j];
    int   n = s_idx[j];
    acc = fmaf(a, fb[(size_t)n * CC + c], acc);
  }
  if (g == 1) s_part[c] = acc;
  __syncthreads();
  if (g == 0) {
    float r = (cnt > 0) ? (acc + s_part[c]) : 0.0f;
    out[(size_t)row * CC + c] = r;
  }
}

// ---------------------------------------------------------------------------

extern "C" void kernel_launch(void* const* d_in, const int* in_sizes, int n_in,
                              void* d_out, int out_size, void* d_ws, size_t ws_size,
                              hipStream_t stream) {
  const float* feats = (const float*)d_in[0];
  const float* sloc  = (const float*)d_in[1];
  const float* tloc  = (const float*)d_in[2];
  const int*   smask = (const int*)d_in[3];
  const int*   tmask = (const int*)d_in[4];
  float* out = (float*)d_out;

  // workspace layout (fast path): ~17 MB
  char* p = (char*)d_ws;
  float* u_   = (float*)p;            p += (size_t)BB * MM * 4;
  float* v_   = (float*)p;            p += (size_t)BB * NN * 4;
  int* ecnt   = (int*)p;              p += 256;
  float2* slm = (float2*)p;           p += (size_t)BB * NN * 8;
  float2* tlm = (float2*)p;           p += (size_t)BB * MM * 8;
  unsigned long long* row_bm = (unsigned long long*)p; p += (size_t)BB * MM * 64 * 8;
  unsigned long long* col_bm = (unsigned long long*)p; p += (size_t)BB * NN * 64 * 8;
  size_t required = (size_t)(p - (char*)d_ws);

  if (ws_size >= required) {
    prep_kernel<<<(BB * NN + 255) / 256, 256, 0, stream>>>(
        sloc, tloc, smask, tmask, v_, ecnt, slm, tlm);
    // sweep9 also computes u1 (first lse_row with v0 = 0)
    sweep9_kernel<<<BB * MM / 16, 256, 0, stream>>>(
        slm, tlm, row_bm, ecnt, u_);
    bt_kernel<<<BB * 64, 256, 0, stream>>>(row_bm, col_bm);
    // u1 done; remaining chain: v1, u2, v2, u3, v3
    for (int it = 0; it < 3; ++it) {
      lse_col_kernel<<<BB * NN / 4, 256, 0, stream>>>(slm, tlm, col_bm,
                                                      smask, ecnt, u_, v_);
      if (it < 2)
        lse_row_kernel<<<BB * MM / 4, 256, 0, stream>>>(tlm, slm, row_bm, v_, u_);
    }
    output3_kernel<<<BB * MM, 256, 0, stream>>>(tlm, slm, row_bm,
                                                u_, v_, feats, out);
  } else {
    // fallback: round-1 path (dense re-sweeps), needs only 128 KB
    float* u = (float*)d_ws;
    float* v = u + (size_t)BB * MM;
    init_v_kernel<<<(BB * NN + 255) / 256, 256, 0, stream>>>(v);
    for (int it = 0; it < 3; ++it) {
      u_update_kernel<<<BB * MM / 4, 256, 0, stream>>>(sloc, tloc, smask, tmask, v, u);
      v_update_kernel<<<BB * NN / 4, 256, 0, stream>>>(sloc, tloc, smask, tmask, u, v);
    }
    output_kernel<<<BB * MM, 256, 0, stream>>>(sloc, tloc, smask, tmask, u, v, feats, out);
  }
}